// Round 6
// baseline (99.717 us; speedup 1.0000x reference)
//
#include <hip/hip_runtime.h>
#include <math.h>

#define B 8
#define N 2048
#define FIN 128
#define FOUT 64
#define NS 0.2f
#define K 1024
#define KP1 1025
#define NCH 64
#define CHS 32
#define NCHP1 65

// monotone bucket map: bucketOf(x) < bucketOf(t) => x < t ; > => x >= t
__device__ __forceinline__ int bucketOf(float v) {
  int q = (int)floorf((v + 8.0f) * 64.0f);  // K=1024 over [-8,8]
  return min(max(q, 0), K - 1);
}

__device__ __forceinline__ int wscan_add_i(int v, int lane) {
#pragma unroll
  for (int off = 1; off < 64; off <<= 1) {
    int o = __shfl_up(v, off, 64);
    v += (lane >= off) ? o : 0;
  }
  return v;
}
__device__ __forceinline__ float wscan_add_f(float v, int lane) {
#pragma unroll
  for (int off = 1; off < 64; off <<= 1) {
    float o = __shfl_up(v, off, 64);
    v += (lane >= off) ? o : 0.f;
  }
  return v;
}

// ---------------------------------------------------------------------------
// K1: h = x@W, s1 = h.a1, s2 = h.a2. W column in 128 VGPRs, x in LDS.
// grid = 512 x 256 (block = 32 rows, wave = 8 rows).
// ---------------------------------------------------------------------------
#define RPB 32
__global__ __launch_bounds__(256, 2) void k_hs(
    const float* __restrict__ x, const float* __restrict__ W,
    const float* __restrict__ a, float* __restrict__ h,
    float* __restrict__ s1, float* __restrict__ s2) {
  __shared__ float xs[RPB * FIN];  // 16 KB
  const int row0 = blockIdx.x * RPB;
  const int lane = threadIdx.x & 63;
  const int wv = threadIdx.x >> 6;

  {
    const float4* src = (const float4*)(x + (size_t)row0 * FIN);
    float4* dst = (float4*)xs;
#pragma unroll
    for (int t = 0; t < 4; ++t)
      dst[threadIdx.x + 256 * t] = src[threadIdx.x + 256 * t];
  }

  float w[FIN];
#pragma unroll
  for (int k = 0; k < FIN; ++k) w[k] = W[k * FOUT + lane];
  const float a1 = a[lane];
  const float a2 = a[FOUT + lane];
  __syncthreads();

  for (int n = 0; n < 8; ++n) {
    const int r = wv * 8 + n;
    const float* xr = xs + r * FIN;
    float ac0 = 0.f, ac1 = 0.f, ac2 = 0.f, ac3 = 0.f;
#pragma unroll
    for (int k4 = 0; k4 < FIN; k4 += 4) {
      float4 xv = *(const float4*)(xr + k4);
      ac0 = fmaf(xv.x, w[k4 + 0], ac0);
      ac1 = fmaf(xv.y, w[k4 + 1], ac1);
      ac2 = fmaf(xv.z, w[k4 + 2], ac2);
      ac3 = fmaf(xv.w, w[k4 + 3], ac3);
    }
    const float acc = (ac0 + ac1) + (ac2 + ac3);
    const int row = row0 + r;
    h[(size_t)row * FOUT + lane] = acc;

    float v1 = acc * a1;
    float v2 = acc * a2;
#pragma unroll
    for (int off = 32; off > 0; off >>= 1) {
      v1 += __shfl_xor(v1, off, 64);
      v2 += __shfl_xor(v2, off, 64);
    }
    if (lane == 0) {
      s1[row] = v1;
      s2[row] = v2;
    }
  }
}

// ---------------------------------------------------------------------------
// K2: one block per batch (1024 thr). Buckets both s1 and s2 (K=1024, shared
// barriers), bucket-prefix sums of u=e^{s1}, uq=e^{0.2 s1}; per-s2-slot
// A=e2/Z, B=eq2/Z via exact boundary-bucket sweep; chunk totals of A*h, B*h
// (CHS=32) and 64-chunk prefix -> PAx/PBx[65][64] per batch.
// ---------------------------------------------------------------------------
__global__ __launch_bounds__(1024) void k_mid(
    const float* __restrict__ s1, const float* __restrict__ s2,
    const float* __restrict__ h,
    float* __restrict__ AslotG, float* __restrict__ BslotG,
    float* __restrict__ elemS2G, int* __restrict__ idx2G,
    int* __restrict__ start2G, float* __restrict__ PAxG,
    float* __restrict__ PBxG) {
  __shared__ int eJ[2048];          // 8 KB  (persists through phase D)
  __shared__ float eS2[2048];       // 8 KB
  __shared__ float region1[8192];   // 32 KB: ABC: eS1|eU|eQ|bsU|bsQ ; DE: ctA|ctB
  __shared__ int cbuf[2048];        // cntA | curA
  __shared__ int cnt2[1024];
  __shared__ int wtI1[16], wtI2[16];
  __shared__ float wtF1[16], wtF2[16];
  __shared__ float totUs;

  float* eS1 = region1;
  float* eU = region1 + 2048;
  float* eQ = region1 + 4096;
  float* bsU = region1 + 6144;
  float* bsQ = region1 + 7168;
  float* ctA = region1;             // aliases eS1/eU (dead after phase C)
  float* ctB = region1 + 4096;
  int* cntA = cbuf;
  int* curA = cbuf + 1024;

  const int b = blockIdx.x;
  const int tid = threadIdx.x;
  const int lane = tid & 63;
  const int wv = tid >> 6;

  // phase 0: zero
  cntA[tid] = 0;
  cnt2[tid] = 0;
  bsU[tid] = 0.f;
  bsQ[tid] = 0.f;
  __syncthreads();

  // phase 1: load keys + histogram both sides
  const float k10 = s1[b * N + tid], k11 = s1[b * N + tid + 1024];
  const float k20 = s2[b * N + tid], k21 = s2[b * N + tid + 1024];
  const int q10 = bucketOf(k10), q11 = bucketOf(k11);
  const int q20 = bucketOf(k20), q21 = bucketOf(k21);
  atomicAdd(&cntA[q10], 1);
  atomicAdd(&cntA[q11], 1);
  atomicAdd(&cnt2[q20], 1);
  atomicAdd(&cnt2[q21], 1);
  __syncthreads();

  // phase 2: exclusive scans of both histograms (1 bucket/thread)
  {
    const int vA = cntA[tid], v2 = cnt2[tid];
    const int iA = wscan_add_i(vA, lane);
    const int i2 = wscan_add_i(v2, lane);
    if (lane == 63) { wtI1[wv] = iA; wtI2[wv] = i2; }
    __syncthreads();
    int cA = 0, c2 = 0;
#pragma unroll
    for (int w = 0; w < 16; ++w) {
      cA += (w < wv) ? wtI1[w] : 0;
      c2 += (w < wv) ? wtI2[w] : 0;
    }
    const int exA = cA + iA - vA, ex2 = c2 + i2 - v2;
    cntA[tid] = exA;   // bucket starts (preserved)
    curA[tid] = exA;   // scatter cursors -> bucket ends after phase 3
    cnt2[tid] = ex2;   // start2 written to global now; cnt2 reused as cursor
    start2G[b * KP1 + tid] = ex2;
    if (tid == 0) start2G[b * KP1 + K] = N;
  }
  __syncthreads();

  // phase 3: scatter both sides (+ exps + bucket-sum atomics for s1 side)
  {
    int sl = atomicAdd(&curA[q10], 1);
    float uv = expf(k10), qv = expf(NS * k10);
    eS1[sl] = k10; eU[sl] = uv; eQ[sl] = qv;
    atomicAdd(&bsU[q10], uv);
    atomicAdd(&bsQ[q10], qv);
    sl = atomicAdd(&curA[q11], 1);
    uv = expf(k11); qv = expf(NS * k11);
    eS1[sl] = k11; eU[sl] = uv; eQ[sl] = qv;
    atomicAdd(&bsU[q11], uv);
    atomicAdd(&bsQ[q11], qv);
    sl = atomicAdd(&cnt2[q20], 1);
    eS2[sl] = k20; eJ[sl] = tid;
    sl = atomicAdd(&cnt2[q21], 1);
    eS2[sl] = k21; eJ[sl] = tid + 1024;
  }
  __syncthreads();

  // phase 4: exclusive scan of bucket sums; flush slot order to global
  {
    elemS2G[b * N + tid] = eS2[tid];
    elemS2G[b * N + tid + 1024] = eS2[tid + 1024];
    idx2G[b * N + tid] = eJ[tid];
    idx2G[b * N + tid + 1024] = eJ[tid + 1024];
    const float vU = bsU[tid], vQ = bsQ[tid];
    const float iU = wscan_add_f(vU, lane);
    const float iQ = wscan_add_f(vQ, lane);
    if (lane == 63) { wtF1[wv] = iU; wtF2[wv] = iQ; }
    __syncthreads();
    float cU = 0.f, cQ = 0.f, tU = 0.f;
#pragma unroll
    for (int w = 0; w < 16; ++w) {
      const float au = wtF1[w], aq = wtF2[w];
      cU += (w < wv) ? au : 0.f;
      cQ += (w < wv) ? aq : 0.f;
      tU += au;
    }
    bsU[tid] = cU + iU - vU;
    bsQ[tid] = cQ + iQ - vQ;
    if (tid == 0) totUs = tU;
  }
  __syncthreads();

  // phase C: per s2-slot A/B (exact boundary-bucket sweep in LDS)
  const float totU = totUs;
#pragma unroll
  for (int e = 0; e < 2; ++e) {
    const int s = tid + e * 1024;
    const float s2v = eS2[s];
    const float t = -s2v;
    const int q = bucketOf(t);
    const int sb = cntA[q], se = curA[q];
    float Pu = bsU[q], Pq = bsQ[q];
    for (int i = sb; i < se; ++i) {
      const bool lt = eS1[i] < t;
      Pu += lt ? eU[i] : 0.f;
      Pq += lt ? eQ[i] : 0.f;
    }
    const float E = expf(s2v), Eq = expf(NS * s2v);
    const float Z = E * (totU - Pu) + Eq * Pq;
    AslotG[b * N + s] = E / Z;
    BslotG[b * N + s] = Eq / Z;
  }
  __syncthreads();

  // phase D: chunk totals of A*h, B*h (region1 now ctA/ctB)
  for (int ch = wv * 4; ch < wv * 4 + 4; ++ch) {
    float accA = 0.f, accB = 0.f;
    for (int rr = 0; rr < CHS; ++rr) {
      const int s = ch * CHS + rr;
      const int j = eJ[s];
      const float av = AslotG[b * N + s];
      const float bv = BslotG[b * N + s];
      const float hv = h[((size_t)b * N + j) * FOUT + lane];
      accA = fmaf(av, hv, accA);
      accB = fmaf(bv, hv, accB);
    }
    ctA[ch * 64 + lane] = accA;
    ctB[ch * 64 + lane] = accB;
  }
  __syncthreads();

  // phase E: exclusive chunk prefix -> PAx/PBx (plus totals at [NCH])
  if (tid < 128) {
    const int f = tid & 63;
    if (tid < 64) {
      float run = 0.f;
      for (int ch = 0; ch < NCH; ++ch) {
        PAxG[((size_t)b * NCHP1 + ch) * FOUT + f] = run;
        run += ctA[ch * 64 + f];
      }
      PAxG[((size_t)b * NCHP1 + NCH) * FOUT + f] = run;
    } else {
      float run = 0.f;
      for (int ch = 0; ch < NCH; ++ch) {
        PBxG[((size_t)b * NCHP1 + ch) * FOUT + f] = run;
        run += ctB[ch * 64 + f];
      }
      PBxG[((size_t)b * NCHP1 + NCH) * FOUT + f] = run;
    }
  }
}

// ---------------------------------------------------------------------------
// K3: per row i (one wave): single combined sweep from chunk base of sb to se:
// take slot if (s < sb) || (s2 < t). sa = totA - PAx[chb] - accA ;
// pb = PBx[chb] + accB ; out = lrelu(u*sa + uq*pb).
// grid = B*N/4 x 256.
// ---------------------------------------------------------------------------
__global__ void k_out(const float* __restrict__ s1,
                      const int* __restrict__ start2G,
                      const float* __restrict__ elemS2G,
                      const int* __restrict__ idx2G,
                      const float* __restrict__ AslotG,
                      const float* __restrict__ BslotG,
                      const float* __restrict__ h,
                      const float* __restrict__ PAxG,
                      const float* __restrict__ PBxG,
                      float* __restrict__ out) {
  const int wv = threadIdx.x >> 6;
  const int lane = threadIdx.x & 63;
  const int row = blockIdx.x * 4 + wv;
  const int b = row >> 11;
  const float s1v = s1[row];
  const float t = -s1v;
  const float uu = expf(s1v), uqv = expf(NS * s1v);
  const int q = bucketOf(t);
  const int sb = start2G[b * KP1 + q];
  const int se = start2G[b * KP1 + q + 1];
  const int chb = sb >> 5;  // CHS = 32
  const float PAv = PAxG[((size_t)b * NCHP1 + chb) * FOUT + lane];
  const float PBv = PBxG[((size_t)b * NCHP1 + chb) * FOUT + lane];
  const float totA = PAxG[((size_t)b * NCHP1 + NCH) * FOUT + lane];

  float accA = 0.f, accB = 0.f;
  for (int s = chb * CHS; s < se; ++s) {
    const bool take = (s < sb) || (elemS2G[b * N + s] < t);
    if (take) {
      const int j = idx2G[b * N + s];
      const float hv = h[((size_t)b * N + j) * FOUT + lane];
      accA = fmaf(AslotG[b * N + s], hv, accA);
      accB = fmaf(BslotG[b * N + s], hv, accB);
    }
  }
  const float sa = totA - PAv - accA;
  const float pb = PBv + accB;
  const float v = uu * sa + uqv * pb;
  out[(size_t)row * FOUT + lane] = v >= 0.f ? v : NS * v;
}

extern "C" void kernel_launch(void* const* d_in, const int* in_sizes, int n_in,
                              void* d_out, int out_size, void* d_ws, size_t ws_size,
                              hipStream_t stream) {
  const float* x = (const float*)d_in[0];   // (8,2048,128)
  const float* W = (const float*)d_in[1];   // (128,64)
  const float* a = (const float*)d_in[2];   // (128,1)
  float* out = (float*)d_out;               // (8,2048,64)

  float* ws = (float*)d_ws;
  float* h = ws;                             // B*N*FOUT
  float* s1 = h + (size_t)B * N * FOUT;      // B*N
  float* s2 = s1 + B * N;
  float* elemS2 = s2 + B * N;
  float* Aslot = elemS2 + B * N;
  float* Bslot = Aslot + B * N;
  float* PAx = Bslot + B * N;                // B*65*64
  float* PBx = PAx + (size_t)B * NCHP1 * FOUT;
  int* idx2 = (int*)(PBx + (size_t)B * NCHP1 * FOUT);  // B*N
  int* start2 = idx2 + B * N;                // B*1025

  k_hs<<<B * N / RPB, 256, 0, stream>>>(x, W, a, h, s1, s2);
  k_mid<<<B, 1024, 0, stream>>>(s1, s2, h, Aslot, Bslot, elemS2, idx2,
                                start2, PAx, PBx);
  k_out<<<B * N / 4, 256, 0, stream>>>(s1, start2, elemS2, idx2, Aslot, Bslot,
                                       h, PAx, PBx, out);
}

// Round 7
// 67.787 us; speedup vs baseline: 1.4710x; 1.4710x over previous
//
#include <hip/hip_runtime.h>
#include <math.h>

#define B 8
#define N 2048
#define NP1 2049
#define FIN 128
#define FOUT 64
#define NS 0.2f
#define K 1024
#define KP1 1025
#define NCH 128
#define CHS 16

// monotone bucket map: bucketOf(x) < bucketOf(t) => x < t ; > => x >= t
__device__ __forceinline__ int bucketOf(float v) {
  int q = (int)floorf((v + 8.0f) * 64.0f);  // K=1024 over [-8,8]
  return min(max(q, 0), K - 1);
}

__device__ __forceinline__ int wscan_add_i(int v, int lane) {
#pragma unroll
  for (int off = 1; off < 64; off <<= 1) {
    int o = __shfl_up(v, off, 64);
    v += (lane >= off) ? o : 0;
  }
  return v;
}
__device__ __forceinline__ float wscan_add_f(float v, int lane) {
#pragma unroll
  for (int off = 1; off < 64; off <<= 1) {
    float o = __shfl_up(v, off, 64);
    v += (lane >= off) ? o : 0.f;
  }
  return v;
}

// ---------------------------------------------------------------------------
// K1: h = x@W, s1 = h.a1, s2 = h.a2. W column in 128 VGPRs, x in LDS.
// grid = 512 x 256 (block = 32 rows, wave = 8 rows).
// ---------------------------------------------------------------------------
#define RPB 32
__global__ __launch_bounds__(256, 2) void k_hs(
    const float* __restrict__ x, const float* __restrict__ W,
    const float* __restrict__ a, float* __restrict__ h,
    float* __restrict__ s1, float* __restrict__ s2) {
  __shared__ float xs[RPB * FIN];  // 16 KB
  const int row0 = blockIdx.x * RPB;
  const int lane = threadIdx.x & 63;
  const int wv = threadIdx.x >> 6;

  {
    const float4* src = (const float4*)(x + (size_t)row0 * FIN);
    float4* dst = (float4*)xs;
#pragma unroll
    for (int t = 0; t < 4; ++t)
      dst[threadIdx.x + 256 * t] = src[threadIdx.x + 256 * t];
  }

  float w[FIN];
#pragma unroll
  for (int k = 0; k < FIN; ++k) w[k] = W[k * FOUT + lane];
  const float a1 = a[lane];
  const float a2 = a[FOUT + lane];
  __syncthreads();

  for (int n = 0; n < 8; ++n) {
    const int r = wv * 8 + n;
    const float* xr = xs + r * FIN;
    float ac0 = 0.f, ac1 = 0.f, ac2 = 0.f, ac3 = 0.f;
#pragma unroll
    for (int k4 = 0; k4 < FIN; k4 += 4) {
      float4 xv = *(const float4*)(xr + k4);
      ac0 = fmaf(xv.x, w[k4 + 0], ac0);
      ac1 = fmaf(xv.y, w[k4 + 1], ac1);
      ac2 = fmaf(xv.z, w[k4 + 2], ac2);
      ac3 = fmaf(xv.w, w[k4 + 3], ac3);
    }
    const float acc = (ac0 + ac1) + (ac2 + ac3);
    const int row = row0 + r;
    h[(size_t)row * FOUT + lane] = acc;

    float v1 = acc * a1;
    float v2 = acc * a2;
#pragma unroll
    for (int off = 32; off > 0; off >>= 1) {
      v1 += __shfl_xor(v1, off, 64);
      v2 += __shfl_xor(v2, off, 64);
    }
    if (lane == 0) {
      s1[row] = v1;
      s2[row] = v2;
    }
  }
}

// ---------------------------------------------------------------------------
// K2: counting-sort bucketing (K=1024). grid = 2*B x 1024 threads.
// type 0 (s1): elemS1/elemU/elemUq in bucket order, start1, slot-prefix of
//              u=e^{s1}, uq=e^{0.2 s1} (exclusive, [N]=total).
// type 1 (s2): elemS2/idx2 in bucket order, start2.
// ---------------------------------------------------------------------------
__global__ __launch_bounds__(1024) void k_bucket(
    const float* __restrict__ s1, const float* __restrict__ s2,
    int* __restrict__ start1, float* __restrict__ elemS1,
    float* __restrict__ elemU, float* __restrict__ elemUq,
    float* __restrict__ slotPrefU, float* __restrict__ slotPrefQ,
    int* __restrict__ start2, float* __restrict__ elemS2,
    int* __restrict__ idx2) {
  __shared__ int cnt[K];
  __shared__ int cur[K];
  __shared__ float eS[N];   // keys in bucket order
  __shared__ float eU[N];   // type0: e^{s1}
  __shared__ float eQ[N];   // type0: e^{0.2 s1}
  __shared__ int eJ[N];     // type1: original index
  __shared__ int wtI[16];
  __shared__ float wtU[16], wtQ[16];

  const int type = blockIdx.x & 1;
  const int b = blockIdx.x >> 1;
  const int tid = threadIdx.x;
  const int lane = tid & 63;
  const int wv = tid >> 6;
  const float* key = (type ? s2 : s1) + b * N;

  cnt[tid] = 0;
  __syncthreads();
  const float k0 = key[tid], k1 = key[tid + 1024];
  const int q0 = bucketOf(k0), q1 = bucketOf(k1);
  atomicAdd(&cnt[q0], 1);
  atomicAdd(&cnt[q1], 1);
  __syncthreads();

  // exclusive scan of cnt[1024] (1/thread)
  {
    const int v = cnt[tid];
    const int incl = wscan_add_i(v, lane);
    if (lane == 63) wtI[wv] = incl;
    __syncthreads();
    int cross = 0;
#pragma unroll
    for (int w = 0; w < 16; ++w) cross += (w < wv) ? wtI[w] : 0;
    const int ex = cross + incl - v;
    cnt[tid] = ex;
    cur[tid] = ex;
  }
  __syncthreads();

  // scatter (intra-bucket order arbitrary -> ulp-level reassociation only)
  if (type == 0) {
    int sl = atomicAdd(&cur[q0], 1);
    eS[sl] = k0; eU[sl] = expf(k0); eQ[sl] = expf(NS * k0);
    sl = atomicAdd(&cur[q1], 1);
    eS[sl] = k1; eU[sl] = expf(k1); eQ[sl] = expf(NS * k1);
  } else {
    int sl = atomicAdd(&cur[q0], 1);
    eS[sl] = k0; eJ[sl] = tid;
    sl = atomicAdd(&cur[q1], 1);
    eS[sl] = k1; eJ[sl] = tid + 1024;
  }
  __syncthreads();

  if (type == 1) {
    elemS2[b * N + tid] = eS[tid];
    elemS2[b * N + tid + 1024] = eS[tid + 1024];
    idx2[b * N + tid] = eJ[tid];
    idx2[b * N + tid + 1024] = eJ[tid + 1024];
    start2[b * KP1 + tid] = cnt[tid];
    if (tid == 0) start2[b * KP1 + K] = N;
    return;
  }

  elemS1[b * N + tid] = eS[tid];
  elemS1[b * N + tid + 1024] = eS[tid + 1024];
  elemU[b * N + tid] = eU[tid];
  elemU[b * N + tid + 1024] = eU[tid + 1024];
  elemUq[b * N + tid] = eQ[tid];
  elemUq[b * N + tid + 1024] = eQ[tid + 1024];
  start1[b * KP1 + tid] = cnt[tid];
  if (tid == 0) start1[b * KP1 + K] = N;

  // exclusive slot-prefix of eU,eQ (2 elems/thread, wave scan + cross-wave)
  const float u0 = eU[2 * tid], u1 = eU[2 * tid + 1];
  const float g0 = eQ[2 * tid], g1 = eQ[2 * tid + 1];
  const float locU = u0 + u1, locQ = g0 + g1;
  const float iU = wscan_add_f(locU, lane);
  const float iQ = wscan_add_f(locQ, lane);
  if (lane == 63) { wtU[wv] = iU; wtQ[wv] = iQ; }
  __syncthreads();
  float crU = 0.f, crQ = 0.f, totU = 0.f, totQ = 0.f;
#pragma unroll
  for (int w = 0; w < 16; ++w) {
    const float au = wtU[w], aq = wtQ[w];
    crU += (w < wv) ? au : 0.f;
    crQ += (w < wv) ? aq : 0.f;
    totU += au; totQ += aq;
  }
  const float exU = crU + iU - locU, exQ = crQ + iQ - locQ;
  slotPrefU[b * NP1 + 2 * tid] = exU;
  slotPrefU[b * NP1 + 2 * tid + 1] = exU + u0;
  slotPrefQ[b * NP1 + 2 * tid] = exQ;
  slotPrefQ[b * NP1 + 2 * tid + 1] = exQ + g0;
  if (tid == 0) { slotPrefU[b * NP1 + N] = totU; slotPrefQ[b * NP1 + N] = totQ; }
}

// ---------------------------------------------------------------------------
// K3: per s2-slot: Z via bucket-prefix + exact boundary-bucket sweep;
//     Aslot = e2/Z, Bslot = eq2/Z.  grid = B*N/256 x 256.
// ---------------------------------------------------------------------------
__global__ void k_z(const float* __restrict__ elemS1, const float* __restrict__ elemU,
                    const float* __restrict__ elemUq, const float* __restrict__ slotPrefU,
                    const float* __restrict__ slotPrefQ, const int* __restrict__ start1,
                    const float* __restrict__ elemS2,
                    float* __restrict__ Aslot, float* __restrict__ Bslot) {
  const int g = blockIdx.x * 256 + threadIdx.x;
  const int b = g >> 11;
  const int s = g & (N - 1);
  const float s2v = elemS2[b * N + s];
  const float t = -s2v;
  const int q = bucketOf(t);
  const int sb = start1[b * KP1 + q], se = start1[b * KP1 + q + 1];
  float Pu = slotPrefU[b * NP1 + sb];
  float Pq = slotPrefQ[b * NP1 + sb];
  for (int i = sb; i < se; ++i) {
    const bool lt = elemS1[b * N + i] < t;
    Pu += lt ? elemU[b * N + i] : 0.f;
    Pq += lt ? elemUq[b * N + i] : 0.f;
  }
  const float totU = slotPrefU[b * NP1 + N];
  const float E = expf(s2v), Eq = expf(NS * s2v);
  const float Z = E * (totU - Pu) + Eq * Pq;
  Aslot[b * N + s] = E / Z;
  Bslot[b * N + s] = Eq / Z;
}

// ---------------------------------------------------------------------------
// K4: chunk totals of A*h, B*h in slot order. CHS=16, wave = one chunk.
// Gather-then-accumulate (16 independent idx->h chains). grid = B*32 x 256.
// ---------------------------------------------------------------------------
__global__ void k_scan1(const float* __restrict__ Aslot, const float* __restrict__ Bslot,
                        const float* __restrict__ h, const int* __restrict__ idx2,
                        float* __restrict__ ctA, float* __restrict__ ctB) {
  const int b = blockIdx.x >> 5;
  const int chunk = (blockIdx.x & 31) * 4 + (threadIdx.x >> 6);
  const int f = threadIdx.x & 63;
  const int s0 = chunk * CHS;

  float hv[CHS], av[CHS], bv[CHS];
#pragma unroll
  for (int rr = 0; rr < CHS; ++rr) {
    const int s = s0 + rr;
    const int j = idx2[b * N + s];
    hv[rr] = h[((size_t)b * N + j) * FOUT + f];
    av[rr] = Aslot[b * N + s];
    bv[rr] = Bslot[b * N + s];
  }
  float ta = 0.f, tb = 0.f;
#pragma unroll
  for (int rr = 0; rr < CHS; ++rr) {
    ta = fmaf(av[rr], hv[rr], ta);
    tb = fmaf(bv[rr], hv[rr], tb);
  }
  ctA[(b * NCH + chunk) * FOUT + f] = ta;
  ctB[(b * NCH + chunk) * FOUT + f] = tb;
}

// ---------------------------------------------------------------------------
// K5: slot-level PB (prefix of B*h) and SA (suffix of A*h) from chunk totals.
// Chunk totals staged in LDS (64 KB). grid = B*32 x 256.
// ---------------------------------------------------------------------------
__global__ __launch_bounds__(256) void k_scan2(
    const float* __restrict__ Aslot, const float* __restrict__ Bslot,
    const float* __restrict__ h, const int* __restrict__ idx2,
    const float* __restrict__ ctA, const float* __restrict__ ctB,
    float* __restrict__ SA, float* __restrict__ PB) {
  __shared__ float cA[NCH * FOUT];  // 32 KB
  __shared__ float cB[NCH * FOUT];  // 32 KB
  const int b = blockIdx.x >> 5;
  const int chunk = (blockIdx.x & 31) * 4 + (threadIdx.x >> 6);
  const int f = threadIdx.x & 63;
  const int s0 = chunk * CHS;

  for (int t = threadIdx.x; t < NCH * FOUT; t += 256) {
    cA[t] = ctA[b * NCH * FOUT + t];
    cB[t] = ctB[b * NCH * FOUT + t];
  }

  // gather this chunk's operands while LDS stage completes
  float hv[CHS], av[CHS], bv[CHS];
#pragma unroll
  for (int rr = 0; rr < CHS; ++rr) {
    const int s = s0 + rr;
    const int j = idx2[b * N + s];
    hv[rr] = h[((size_t)b * N + j) * FOUT + f];
    av[rr] = Aslot[b * N + s];
    bv[rr] = Bslot[b * N + s];
  }
  __syncthreads();

  float offA = 0.f, offB = 0.f;
#pragma unroll 8
  for (int c2 = 0; c2 < NCH; ++c2) {
    const float va = cA[c2 * FOUT + f];
    const float vb = cB[c2 * FOUT + f];
    if (c2 > chunk) offA += va;
    if (c2 < chunk) offB += vb;
  }

  float run = offB;
#pragma unroll
  for (int rr = 0; rr < CHS; ++rr) {
    run = fmaf(bv[rr], hv[rr], run);
    PB[((size_t)b * NP1 + s0 + rr + 1) * FOUT + f] = run;
  }
  run = offA;
#pragma unroll
  for (int rr = CHS - 1; rr >= 0; --rr) {
    run = fmaf(av[rr], hv[rr], run);
    SA[((size_t)b * NP1 + s0 + rr) * FOUT + f] = run;
  }
  if (chunk == 0) {
    PB[((size_t)b * NP1 + 0) * FOUT + f] = 0.f;
    SA[((size_t)b * NP1 + N) * FOUT + f] = 0.f;
  }
}

// ---------------------------------------------------------------------------
// K6: per row i (one wave): q = bucket(-s1_i); sa = SA[se], pb = PB[sb],
//     exact sweep of boundary bucket [sb,se); out = lrelu(u*sa + uq*pb).
// grid = B*N/4 x 256.
// ---------------------------------------------------------------------------
__global__ void k_out(const float* __restrict__ s1,
                      const int* __restrict__ start2,
                      const float* __restrict__ elemS2,
                      const int* __restrict__ idx2,
                      const float* __restrict__ Aslot,
                      const float* __restrict__ Bslot,
                      const float* __restrict__ h,
                      const float* __restrict__ SA,
                      const float* __restrict__ PB,
                      float* __restrict__ out) {
  const int wv = threadIdx.x >> 6;
  const int lane = threadIdx.x & 63;
  const int row = blockIdx.x * 4 + wv;
  const int b = row >> 11;
  const float s1v = s1[row];
  const float t = -s1v;
  const int q = bucketOf(t);
  const int sb = start2[b * KP1 + q];
  const int se = start2[b * KP1 + q + 1];

  float sa = SA[((size_t)b * NP1 + se) * FOUT + lane];  // all buckets > q
  float pb = PB[((size_t)b * NP1 + sb) * FOUT + lane];  // all buckets < q
  for (int s = sb; s < se; ++s) {
    const float s2v = elemS2[b * N + s];
    const int j = idx2[b * N + s];
    const float hv = h[((size_t)b * N + j) * FOUT + lane];
    if (s2v >= t) sa = fmaf(Aslot[b * N + s], hv, sa);
    else          pb = fmaf(Bslot[b * N + s], hv, pb);
  }
  const float uu = expf(s1v), uqv = expf(NS * s1v);
  const float v = uu * sa + uqv * pb;
  out[(size_t)row * FOUT + lane] = v >= 0.f ? v : NS * v;
}

extern "C" void kernel_launch(void* const* d_in, const int* in_sizes, int n_in,
                              void* d_out, int out_size, void* d_ws, size_t ws_size,
                              hipStream_t stream) {
  const float* x = (const float*)d_in[0];   // (8,2048,128)
  const float* W = (const float*)d_in[1];   // (128,64)
  const float* a = (const float*)d_in[2];   // (128,1)
  float* out = (float*)d_out;               // (8,2048,64)

  float* ws = (float*)d_ws;
  float* h = ws;                             // B*N*FOUT
  float* s1 = h + (size_t)B * N * FOUT;      // B*N each
  float* s2 = s1 + B * N;
  float* elemS1 = s2 + B * N;
  float* elemU = elemS1 + B * N;
  float* elemUq = elemU + B * N;
  float* elemS2 = elemUq + B * N;
  float* Aslot = elemS2 + B * N;
  float* Bslot = Aslot + B * N;
  float* slotPrefU = Bslot + B * N;          // B*NP1
  float* slotPrefQ = slotPrefU + B * NP1;
  int* idx2 = (int*)(slotPrefQ + B * NP1);   // B*N
  int* start1 = idx2 + B * N;                // B*KP1
  int* start2 = start1 + B * KP1;
  float* ctA = (float*)(start2 + B * KP1);   // B*NCH*64
  float* ctB = ctA + (size_t)B * NCH * FOUT;
  float* SA = ctB + (size_t)B * NCH * FOUT;  // B*NP1*64
  float* PB = SA + (size_t)B * NP1 * FOUT;

  k_hs<<<B * N / RPB, 256, 0, stream>>>(x, W, a, h, s1, s2);
  k_bucket<<<2 * B, 1024, 0, stream>>>(s1, s2, start1, elemS1, elemU, elemUq,
                                       slotPrefU, slotPrefQ, start2, elemS2, idx2);
  k_z<<<B * (N / 256), 256, 0, stream>>>(elemS1, elemU, elemUq, slotPrefU,
                                         slotPrefQ, start1, elemS2, Aslot, Bslot);
  k_scan1<<<B * 32, 256, 0, stream>>>(Aslot, Bslot, h, idx2, ctA, ctB);
  k_scan2<<<B * 32, 256, 0, stream>>>(Aslot, Bslot, h, idx2, ctA, ctB, SA, PB);
  k_out<<<B * N / 4, 256, 0, stream>>>(s1, start2, elemS2, idx2, Aslot, Bslot,
                                       h, SA, PB, out);
}

// Round 8
// 67.785 us; speedup vs baseline: 1.4711x; 1.0000x over previous
//
#include <hip/hip_runtime.h>
#include <math.h>

#define B 8
#define N 2048
#define NP1 2049
#define FIN 128
#define FOUT 64
#define NS 0.2f
#define K 1024
#define KP1 1025
#define NCH 64
#define CHS 32

// monotone bucket map: bucketOf(x) < bucketOf(t) => x < t ; > => x >= t
__device__ __forceinline__ int bucketOf(float v) {
  int q = (int)floorf((v + 8.0f) * 64.0f);  // K=1024 over [-8,8]
  return min(max(q, 0), K - 1);
}

__device__ __forceinline__ int wscan_add_i(int v, int lane) {
#pragma unroll
  for (int off = 1; off < 64; off <<= 1) {
    int o = __shfl_up(v, off, 64);
    v += (lane >= off) ? o : 0;
  }
  return v;
}
__device__ __forceinline__ float wscan_add_f(float v, int lane) {
#pragma unroll
  for (int off = 1; off < 64; off <<= 1) {
    float o = __shfl_up(v, off, 64);
    v += (lane >= off) ? o : 0.f;
  }
  return v;
}

// ---------------------------------------------------------------------------
// K1: h = x@W, s1 = h.a1, s2 = h.a2. W column in 128 VGPRs, x in LDS.
// grid = 512 x 256 (block = 32 rows, wave = 8 rows).
// ---------------------------------------------------------------------------
#define RPB 32
__global__ __launch_bounds__(256, 2) void k_hs(
    const float* __restrict__ x, const float* __restrict__ W,
    const float* __restrict__ a, float* __restrict__ h,
    float* __restrict__ s1, float* __restrict__ s2) {
  __shared__ float xs[RPB * FIN];  // 16 KB
  const int row0 = blockIdx.x * RPB;
  const int lane = threadIdx.x & 63;
  const int wv = threadIdx.x >> 6;

  {
    const float4* src = (const float4*)(x + (size_t)row0 * FIN);
    float4* dst = (float4*)xs;
#pragma unroll
    for (int t = 0; t < 4; ++t)
      dst[threadIdx.x + 256 * t] = src[threadIdx.x + 256 * t];
  }

  float w[FIN];
#pragma unroll
  for (int k = 0; k < FIN; ++k) w[k] = W[k * FOUT + lane];
  const float a1 = a[lane];
  const float a2 = a[FOUT + lane];
  __syncthreads();

  for (int n = 0; n < 8; ++n) {
    const int r = wv * 8 + n;
    const float* xr = xs + r * FIN;
    float ac0 = 0.f, ac1 = 0.f, ac2 = 0.f, ac3 = 0.f;
#pragma unroll
    for (int k4 = 0; k4 < FIN; k4 += 4) {
      float4 xv = *(const float4*)(xr + k4);
      ac0 = fmaf(xv.x, w[k4 + 0], ac0);
      ac1 = fmaf(xv.y, w[k4 + 1], ac1);
      ac2 = fmaf(xv.z, w[k4 + 2], ac2);
      ac3 = fmaf(xv.w, w[k4 + 3], ac3);
    }
    const float acc = (ac0 + ac1) + (ac2 + ac3);
    const int row = row0 + r;
    h[(size_t)row * FOUT + lane] = acc;

    float v1 = acc * a1;
    float v2 = acc * a2;
#pragma unroll
    for (int off = 32; off > 0; off >>= 1) {
      v1 += __shfl_xor(v1, off, 64);
      v2 += __shfl_xor(v2, off, 64);
    }
    if (lane == 0) {
      s1[row] = v1;
      s2[row] = v2;
    }
  }
}

// ---------------------------------------------------------------------------
// K2: one block per batch (1024 thr). Buckets s1 AND s2 (K=1024, in LDS),
// bucket-level sums + prefix of u=e^{s1}, uq=e^{0.2 s1}; per-s2-slot
// A=e2/Z, B=eq2/Z via exact boundary-bucket sweep (all LDS).
// Outputs: elemS2, idx2, start2, Aslot, Bslot.  (round-6 phases 0..C)
// ---------------------------------------------------------------------------
__global__ __launch_bounds__(1024) void k_midZ(
    const float* __restrict__ s1, const float* __restrict__ s2,
    float* __restrict__ AslotG, float* __restrict__ BslotG,
    float* __restrict__ elemS2G, int* __restrict__ idx2G,
    int* __restrict__ start2G) {
  __shared__ float eS1[2048], eU[2048], eQ[2048];   // 24 KB
  __shared__ float eS2[2048];                       // 8 KB
  __shared__ int eJ[2048];                          // 8 KB
  __shared__ float bsU[K], bsQ[K];                  // 8 KB
  __shared__ int cntA[K], curA[K], cnt2[K];         // 12 KB
  __shared__ int wtI1[16], wtI2[16];
  __shared__ float wtF1[16], wtF2[16];
  __shared__ float totUs;

  const int b = blockIdx.x;
  const int tid = threadIdx.x;
  const int lane = tid & 63;
  const int wv = tid >> 6;

  // phase 0: zero
  cntA[tid] = 0;
  cnt2[tid] = 0;
  bsU[tid] = 0.f;
  bsQ[tid] = 0.f;
  __syncthreads();

  // phase 1: load keys + histogram both sides
  const float k10 = s1[b * N + tid], k11 = s1[b * N + tid + 1024];
  const float k20 = s2[b * N + tid], k21 = s2[b * N + tid + 1024];
  const int q10 = bucketOf(k10), q11 = bucketOf(k11);
  const int q20 = bucketOf(k20), q21 = bucketOf(k21);
  atomicAdd(&cntA[q10], 1);
  atomicAdd(&cntA[q11], 1);
  atomicAdd(&cnt2[q20], 1);
  atomicAdd(&cnt2[q21], 1);
  __syncthreads();

  // phase 2: exclusive scans of both histograms (1 bucket/thread)
  {
    const int vA = cntA[tid], v2 = cnt2[tid];
    const int iA = wscan_add_i(vA, lane);
    const int i2 = wscan_add_i(v2, lane);
    if (lane == 63) { wtI1[wv] = iA; wtI2[wv] = i2; }
    __syncthreads();
    int cA = 0, c2 = 0;
#pragma unroll
    for (int w = 0; w < 16; ++w) {
      cA += (w < wv) ? wtI1[w] : 0;
      c2 += (w < wv) ? wtI2[w] : 0;
    }
    const int exA = cA + iA - vA, ex2 = c2 + i2 - v2;
    cntA[tid] = exA;   // bucket starts (preserved)
    curA[tid] = exA;   // cursors -> bucket ends after phase 3
    cnt2[tid] = ex2;   // cursor for s2 side
    start2G[b * KP1 + tid] = ex2;
    if (tid == 0) start2G[b * KP1 + K] = N;
  }
  __syncthreads();

  // phase 3: scatter both sides (+ exps + bucket-sum atomics for s1 side)
  {
    int sl = atomicAdd(&curA[q10], 1);
    float uv = expf(k10), qv = expf(NS * k10);
    eS1[sl] = k10; eU[sl] = uv; eQ[sl] = qv;
    atomicAdd(&bsU[q10], uv);
    atomicAdd(&bsQ[q10], qv);
    sl = atomicAdd(&curA[q11], 1);
    uv = expf(k11); qv = expf(NS * k11);
    eS1[sl] = k11; eU[sl] = uv; eQ[sl] = qv;
    atomicAdd(&bsU[q11], uv);
    atomicAdd(&bsQ[q11], qv);
    sl = atomicAdd(&cnt2[q20], 1);
    eS2[sl] = k20; eJ[sl] = tid;
    sl = atomicAdd(&cnt2[q21], 1);
    eS2[sl] = k21; eJ[sl] = tid + 1024;
  }
  __syncthreads();

  // phase 4: exclusive scan of bucket sums; flush s2 slot order to global
  {
    elemS2G[b * N + tid] = eS2[tid];
    elemS2G[b * N + tid + 1024] = eS2[tid + 1024];
    idx2G[b * N + tid] = eJ[tid];
    idx2G[b * N + tid + 1024] = eJ[tid + 1024];
    const float vU = bsU[tid], vQ = bsQ[tid];
    const float iU = wscan_add_f(vU, lane);
    const float iQ = wscan_add_f(vQ, lane);
    if (lane == 63) { wtF1[wv] = iU; wtF2[wv] = iQ; }
    __syncthreads();
    float cU = 0.f, cQ = 0.f, tU = 0.f;
#pragma unroll
    for (int w = 0; w < 16; ++w) {
      const float au = wtF1[w], aq = wtF2[w];
      cU += (w < wv) ? au : 0.f;
      cQ += (w < wv) ? aq : 0.f;
      tU += au;
    }
    bsU[tid] = cU + iU - vU;
    bsQ[tid] = cQ + iQ - vQ;
    if (tid == 0) totUs = tU;
  }
  __syncthreads();

  // phase C: per s2-slot A/B (exact boundary-bucket sweep in LDS)
  const float totU = totUs;
#pragma unroll
  for (int e = 0; e < 2; ++e) {
    const int s = tid + e * 1024;
    const float s2v = eS2[s];
    const float t = -s2v;
    const int q = bucketOf(t);
    const int sb = cntA[q], se = curA[q];
    float Pu = bsU[q], Pq = bsQ[q];
    for (int i = sb; i < se; ++i) {
      const bool lt = eS1[i] < t;
      Pu += lt ? eU[i] : 0.f;
      Pq += lt ? eQ[i] : 0.f;
    }
    const float E = expf(s2v), Eq = expf(NS * s2v);
    const float Z = E * (totU - Pu) + Eq * Pq;
    AslotG[b * N + s] = E / Z;
    BslotG[b * N + s] = Eq / Z;
  }
}

// ---------------------------------------------------------------------------
// K3: chunk totals of A*h, B*h in slot order. CHS=32, wave = one chunk,
// two 16-deep independent gather groups. grid = B*16 x 256.
// ---------------------------------------------------------------------------
__global__ void k_scan1(const float* __restrict__ Aslot, const float* __restrict__ Bslot,
                        const float* __restrict__ h, const int* __restrict__ idx2,
                        float* __restrict__ ctA, float* __restrict__ ctB) {
  const int b = blockIdx.x >> 4;
  const int chunk = (blockIdx.x & 15) * 4 + (threadIdx.x >> 6);
  const int f = threadIdx.x & 63;
  const int s0 = chunk * CHS;

  float ta = 0.f, tb = 0.f;
#pragma unroll
  for (int g = 0; g < 2; ++g) {
    float hv[16], av[16], bv[16];
#pragma unroll
    for (int rr = 0; rr < 16; ++rr) {
      const int s = s0 + g * 16 + rr;
      const int j = idx2[b * N + s];
      hv[rr] = h[((size_t)b * N + j) * FOUT + f];
      av[rr] = Aslot[b * N + s];
      bv[rr] = Bslot[b * N + s];
    }
#pragma unroll
    for (int rr = 0; rr < 16; ++rr) {
      ta = fmaf(av[rr], hv[rr], ta);
      tb = fmaf(bv[rr], hv[rr], tb);
    }
  }
  ctA[(b * NCH + chunk) * FOUT + f] = ta;
  ctB[(b * NCH + chunk) * FOUT + f] = tb;
}

// ---------------------------------------------------------------------------
// K4: slot-level PB (prefix of B*h) and SA (suffix of A*h) from chunk totals.
// 32 KB LDS staging. grid = B*16 x 256.
// ---------------------------------------------------------------------------
__global__ __launch_bounds__(256) void k_scan2(
    const float* __restrict__ Aslot, const float* __restrict__ Bslot,
    const float* __restrict__ h, const int* __restrict__ idx2,
    const float* __restrict__ ctA, const float* __restrict__ ctB,
    float* __restrict__ SA, float* __restrict__ PB) {
  __shared__ float cA[NCH * FOUT];  // 16 KB
  __shared__ float cB[NCH * FOUT];  // 16 KB
  const int b = blockIdx.x >> 4;
  const int chunk = (blockIdx.x & 15) * 4 + (threadIdx.x >> 6);
  const int f = threadIdx.x & 63;
  const int s0 = chunk * CHS;

  for (int t = threadIdx.x; t < NCH * FOUT; t += 256) {
    cA[t] = ctA[b * NCH * FOUT + t];
    cB[t] = ctB[b * NCH * FOUT + t];
  }
  __syncthreads();

  float offA = 0.f, offB = 0.f;
#pragma unroll 8
  for (int c2 = 0; c2 < NCH; ++c2) {
    const float va = cA[c2 * FOUT + f];
    const float vb = cB[c2 * FOUT + f];
    if (c2 > chunk) offA += va;
    if (c2 < chunk) offB += vb;
  }

  // forward prefix (PB), two 16-deep gather groups
  float run = offB;
#pragma unroll
  for (int g = 0; g < 2; ++g) {
    float hv[16], bv[16];
#pragma unroll
    for (int rr = 0; rr < 16; ++rr) {
      const int s = s0 + g * 16 + rr;
      const int j = idx2[b * N + s];
      hv[rr] = h[((size_t)b * N + j) * FOUT + f];
      bv[rr] = Bslot[b * N + s];
    }
#pragma unroll
    for (int rr = 0; rr < 16; ++rr) {
      run = fmaf(bv[rr], hv[rr], run);
      PB[((size_t)b * NP1 + s0 + g * 16 + rr + 1) * FOUT + f] = run;
    }
  }
  // backward suffix (SA)
  run = offA;
#pragma unroll
  for (int g = 1; g >= 0; --g) {
    float hv[16], av[16];
#pragma unroll
    for (int rr = 0; rr < 16; ++rr) {
      const int s = s0 + g * 16 + rr;
      const int j = idx2[b * N + s];
      hv[rr] = h[((size_t)b * N + j) * FOUT + f];
      av[rr] = Aslot[b * N + s];
    }
#pragma unroll
    for (int rr = 15; rr >= 0; --rr) {
      run = fmaf(av[rr], hv[rr], run);
      SA[((size_t)b * NP1 + s0 + g * 16 + rr) * FOUT + f] = run;
    }
  }
  if (chunk == 0) {
    PB[((size_t)b * NP1 + 0) * FOUT + f] = 0.f;
    SA[((size_t)b * NP1 + N) * FOUT + f] = 0.f;
  }
}

// ---------------------------------------------------------------------------
// K5: per row i (one wave): q = bucket(-s1_i); sa = SA[se], pb = PB[sb],
//     exact sweep of boundary bucket [sb,se); out = lrelu(u*sa + uq*pb).
// grid = B*N/4 x 256.
// ---------------------------------------------------------------------------
__global__ void k_out(const float* __restrict__ s1,
                      const int* __restrict__ start2,
                      const float* __restrict__ elemS2,
                      const int* __restrict__ idx2,
                      const float* __restrict__ Aslot,
                      const float* __restrict__ Bslot,
                      const float* __restrict__ h,
                      const float* __restrict__ SA,
                      const float* __restrict__ PB,
                      float* __restrict__ out) {
  const int wv = threadIdx.x >> 6;
  const int lane = threadIdx.x & 63;
  const int row = blockIdx.x * 4 + wv;
  const int b = row >> 11;
  const float s1v = s1[row];
  const float t = -s1v;
  const int q = bucketOf(t);
  const int sb = start2[b * KP1 + q];
  const int se = start2[b * KP1 + q + 1];

  float sa = SA[((size_t)b * NP1 + se) * FOUT + lane];  // all buckets > q
  float pb = PB[((size_t)b * NP1 + sb) * FOUT + lane];  // all buckets < q
  for (int s = sb; s < se; ++s) {
    const float s2v = elemS2[b * N + s];
    const int j = idx2[b * N + s];
    const float hv = h[((size_t)b * N + j) * FOUT + lane];
    if (s2v >= t) sa = fmaf(Aslot[b * N + s], hv, sa);
    else          pb = fmaf(Bslot[b * N + s], hv, pb);
  }
  const float uu = expf(s1v), uqv = expf(NS * s1v);
  const float v = uu * sa + uqv * pb;
  out[(size_t)row * FOUT + lane] = v >= 0.f ? v : NS * v;
}

extern "C" void kernel_launch(void* const* d_in, const int* in_sizes, int n_in,
                              void* d_out, int out_size, void* d_ws, size_t ws_size,
                              hipStream_t stream) {
  const float* x = (const float*)d_in[0];   // (8,2048,128)
  const float* W = (const float*)d_in[1];   // (128,64)
  const float* a = (const float*)d_in[2];   // (128,1)
  float* out = (float*)d_out;               // (8,2048,64)

  float* ws = (float*)d_ws;
  float* h = ws;                             // B*N*FOUT
  float* s1 = h + (size_t)B * N * FOUT;      // B*N each
  float* s2 = s1 + B * N;
  float* elemS2 = s2 + B * N;
  float* Aslot = elemS2 + B * N;
  float* Bslot = Aslot + B * N;
  int* idx2 = (int*)(Bslot + B * N);         // B*N
  int* start2 = idx2 + B * N;                // B*KP1
  float* ctA = (float*)(start2 + B * KP1);   // B*NCH*64
  float* ctB = ctA + (size_t)B * NCH * FOUT;
  float* SA = ctB + (size_t)B * NCH * FOUT;  // B*NP1*64
  float* PB = SA + (size_t)B * NP1 * FOUT;

  k_hs<<<B * N / RPB, 256, 0, stream>>>(x, W, a, h, s1, s2);
  k_midZ<<<B, 1024, 0, stream>>>(s1, s2, Aslot, Bslot, elemS2, idx2, start2);
  k_scan1<<<B * 16, 256, 0, stream>>>(Aslot, Bslot, h, idx2, ctA, ctB);
  k_scan2<<<B * 16, 256, 0, stream>>>(Aslot, Bslot, h, idx2, ctA, ctB, SA, PB);
  k_out<<<B * N / 4, 256, 0, stream>>>(s1, start2, elemS2, idx2, Aslot, Bslot,
                                       h, SA, PB, out);
}

// Round 9
// 55.421 us; speedup vs baseline: 1.7993x; 1.2231x over previous
//
#include <hip/hip_runtime.h>
#include <math.h>

#define B 8
#define N 2048
#define NP1 2049
#define FIN 128
#define FOUT 64
#define NS 0.2f
#define K 2048
#define KP1 2049
#define NCH 64
#define CHS 32

// monotone bucket map: bucketOf(x) < bucketOf(t) => x < t ; > => x >= t
__device__ __forceinline__ int bucketOf(float v) {
  int q = (int)floorf((v + 8.0f) * 128.0f);  // K=2048 over [-8,8]
  return min(max(q, 0), K - 1);
}

__device__ __forceinline__ int wscan_add_i(int v, int lane) {
#pragma unroll
  for (int off = 1; off < 64; off <<= 1) {
    int o = __shfl_up(v, off, 64);
    v += (lane >= off) ? o : 0;
  }
  return v;
}
__device__ __forceinline__ float wscan_add_f(float v, int lane) {
#pragma unroll
  for (int off = 1; off < 64; off <<= 1) {
    float o = __shfl_up(v, off, 64);
    v += (lane >= off) ? o : 0.f;
  }
  return v;
}

// ---------------------------------------------------------------------------
// K1: h = x@W, s1 = h.a1, s2 = h.a2. W column in 128 VGPRs, x in LDS.
// grid = 512 x 256 (block = 32 rows, wave = 8 rows).
// ---------------------------------------------------------------------------
#define RPB 32
__global__ __launch_bounds__(256, 2) void k_hs(
    const float* __restrict__ x, const float* __restrict__ W,
    const float* __restrict__ a, float* __restrict__ h,
    float* __restrict__ s1, float* __restrict__ s2) {
  __shared__ float xs[RPB * FIN];  // 16 KB
  const int row0 = blockIdx.x * RPB;
  const int lane = threadIdx.x & 63;
  const int wv = threadIdx.x >> 6;

  {
    const float4* src = (const float4*)(x + (size_t)row0 * FIN);
    float4* dst = (float4*)xs;
#pragma unroll
    for (int t = 0; t < 4; ++t)
      dst[threadIdx.x + 256 * t] = src[threadIdx.x + 256 * t];
  }

  float w[FIN];
#pragma unroll
  for (int k = 0; k < FIN; ++k) w[k] = W[k * FOUT + lane];
  const float a1 = a[lane];
  const float a2 = a[FOUT + lane];
  __syncthreads();

  for (int n = 0; n < 8; ++n) {
    const int r = wv * 8 + n;
    const float* xr = xs + r * FIN;
    float ac0 = 0.f, ac1 = 0.f, ac2 = 0.f, ac3 = 0.f;
#pragma unroll
    for (int k4 = 0; k4 < FIN; k4 += 4) {
      float4 xv = *(const float4*)(xr + k4);
      ac0 = fmaf(xv.x, w[k4 + 0], ac0);
      ac1 = fmaf(xv.y, w[k4 + 1], ac1);
      ac2 = fmaf(xv.z, w[k4 + 2], ac2);
      ac3 = fmaf(xv.w, w[k4 + 3], ac3);
    }
    const float acc = (ac0 + ac1) + (ac2 + ac3);
    const int row = row0 + r;
    h[(size_t)row * FOUT + lane] = acc;

    float v1 = acc * a1;
    float v2 = acc * a2;
#pragma unroll
    for (int off = 32; off > 0; off >>= 1) {
      v1 += __shfl_xor(v1, off, 64);
      v2 += __shfl_xor(v2, off, 64);
    }
    if (lane == 0) {
      s1[row] = v1;
      s2[row] = v2;
    }
  }
}

// ---------------------------------------------------------------------------
// K2: counting-sort bucketing (K=2048). grid = 2*B x 1024 threads.
// type 0 (s1): elemS1/elemU/elemUq in bucket order (exps inline), start1,
//              exclusive slot-prefix of u,uq ([N]=total).
// type 1 (s2): elemS2/idx2 in bucket order, start2.
// ---------------------------------------------------------------------------
__global__ __launch_bounds__(1024) void k_bucket(
    const float* __restrict__ s1, const float* __restrict__ s2,
    int* __restrict__ start1, float* __restrict__ elemS1,
    float* __restrict__ elemU, float* __restrict__ elemUq,
    float* __restrict__ slotPrefU, float* __restrict__ slotPrefQ,
    int* __restrict__ start2, float* __restrict__ elemS2,
    int* __restrict__ idx2) {
  __shared__ int cnt[K];     // 8 KB
  __shared__ int cur[K];     // 8 KB
  __shared__ float eS[N];    // 8 KB
  __shared__ float eU[N];    // 8 KB (type0)
  __shared__ float eQ[N];    // 8 KB (type0)
  __shared__ int eJ[N];      // 8 KB (type1)
  __shared__ int wtI[16];
  __shared__ float wtU[16], wtQ[16];

  const int type = blockIdx.x & 1;
  const int b = blockIdx.x >> 1;
  const int tid = threadIdx.x;
  const int lane = tid & 63;
  const int wv = tid >> 6;
  const float* key = (type ? s2 : s1) + b * N;

  cnt[tid] = 0;
  cnt[tid + 1024] = 0;
  __syncthreads();
  const float k0 = key[tid], k1 = key[tid + 1024];
  const int q0 = bucketOf(k0), q1 = bucketOf(k1);
  atomicAdd(&cnt[q0], 1);
  atomicAdd(&cnt[q1], 1);
  __syncthreads();

  // exclusive scan of cnt[2048] (2 entries/thread)
  {
    const int c0 = cnt[2 * tid], c1 = cnt[2 * tid + 1];
    const int loc = c0 + c1;
    const int incl = wscan_add_i(loc, lane);
    if (lane == 63) wtI[wv] = incl;
    __syncthreads();
    int cross = 0;
#pragma unroll
    for (int w = 0; w < 16; ++w) cross += (w < wv) ? wtI[w] : 0;
    const int ex = cross + incl - loc;
    cnt[2 * tid] = ex;       cnt[2 * tid + 1] = ex + c0;
    cur[2 * tid] = ex;       cur[2 * tid + 1] = ex + c0;
  }
  __syncthreads();

  // scatter (intra-bucket order arbitrary -> ulp-level reassociation only)
  if (type == 0) {
    int sl = atomicAdd(&cur[q0], 1);
    eS[sl] = k0; eU[sl] = expf(k0); eQ[sl] = expf(NS * k0);
    sl = atomicAdd(&cur[q1], 1);
    eS[sl] = k1; eU[sl] = expf(k1); eQ[sl] = expf(NS * k1);
  } else {
    int sl = atomicAdd(&cur[q0], 1);
    eS[sl] = k0; eJ[sl] = tid;
    sl = atomicAdd(&cur[q1], 1);
    eS[sl] = k1; eJ[sl] = tid + 1024;
  }
  __syncthreads();

  if (type == 1) {
    elemS2[b * N + tid] = eS[tid];
    elemS2[b * N + tid + 1024] = eS[tid + 1024];
    idx2[b * N + tid] = eJ[tid];
    idx2[b * N + tid + 1024] = eJ[tid + 1024];
    start2[b * KP1 + tid] = cnt[tid];
    start2[b * KP1 + tid + 1024] = cnt[tid + 1024];
    if (tid == 0) start2[b * KP1 + K] = N;
    return;
  }

  elemS1[b * N + tid] = eS[tid];
  elemS1[b * N + tid + 1024] = eS[tid + 1024];
  elemU[b * N + tid] = eU[tid];
  elemU[b * N + tid + 1024] = eU[tid + 1024];
  elemUq[b * N + tid] = eQ[tid];
  elemUq[b * N + tid + 1024] = eQ[tid + 1024];
  start1[b * KP1 + tid] = cnt[tid];
  start1[b * KP1 + tid + 1024] = cnt[tid + 1024];
  if (tid == 0) start1[b * KP1 + K] = N;

  // exclusive slot-prefix of eU,eQ (2 elems/thread)
  const float u0 = eU[2 * tid], u1 = eU[2 * tid + 1];
  const float g0 = eQ[2 * tid], g1 = eQ[2 * tid + 1];
  const float locU = u0 + u1, locQ = g0 + g1;
  const float iU = wscan_add_f(locU, lane);
  const float iQ = wscan_add_f(locQ, lane);
  if (lane == 63) { wtU[wv] = iU; wtQ[wv] = iQ; }
  __syncthreads();
  float crU = 0.f, crQ = 0.f, totU = 0.f, totQ = 0.f;
#pragma unroll
  for (int w = 0; w < 16; ++w) {
    const float au = wtU[w], aq = wtQ[w];
    crU += (w < wv) ? au : 0.f;
    crQ += (w < wv) ? aq : 0.f;
    totU += au; totQ += aq;
  }
  const float exU = crU + iU - locU, exQ = crQ + iQ - locQ;
  slotPrefU[b * NP1 + 2 * tid] = exU;
  slotPrefU[b * NP1 + 2 * tid + 1] = exU + u0;
  slotPrefQ[b * NP1 + 2 * tid] = exQ;
  slotPrefQ[b * NP1 + 2 * tid + 1] = exQ + g0;
  if (tid == 0) { slotPrefU[b * NP1 + N] = totU; slotPrefQ[b * NP1 + N] = totQ; }
}

// ---------------------------------------------------------------------------
// K3: per s2-slot: Z via slot-prefix at bucket start + exact boundary-bucket
//     sweep (avg 1 elem at K=2048); AB[s] = {e2/Z, eq2/Z}. grid = 64 x 256.
// ---------------------------------------------------------------------------
__global__ void k_z(const float* __restrict__ elemS1, const float* __restrict__ elemU,
                    const float* __restrict__ elemUq, const float* __restrict__ slotPrefU,
                    const float* __restrict__ slotPrefQ, const int* __restrict__ start1,
                    const float* __restrict__ elemS2, float2* __restrict__ AB) {
  const int g = blockIdx.x * 256 + threadIdx.x;
  const int b = g >> 11;
  const int s = g & (N - 1);
  const float s2v = elemS2[b * N + s];
  const float t = -s2v;
  const int q = bucketOf(t);
  const int sb = start1[b * KP1 + q], se = start1[b * KP1 + q + 1];
  float Pu = slotPrefU[b * NP1 + sb];
  float Pq = slotPrefQ[b * NP1 + sb];
  for (int i = sb; i < se; ++i) {
    const bool lt = elemS1[b * N + i] < t;
    Pu += lt ? elemU[b * N + i] : 0.f;
    Pq += lt ? elemUq[b * N + i] : 0.f;
  }
  const float totU = slotPrefU[b * NP1 + N];
  const float E = expf(s2v), Eq = expf(NS * s2v);
  const float Z = E * (totU - Pu) + Eq * Pq;
  AB[b * N + s] = make_float2(E / Z, Eq / Z);
}

// ---------------------------------------------------------------------------
// K4: chunk totals of A*h, B*h in slot order AND hperm[s] = h[idx2[s]]
//     (the only random-gather pass). Two 16-deep independent gather groups.
//     grid = B*16 x 256 (wave = one chunk of 32).
// ---------------------------------------------------------------------------
__global__ void k_scan1(const float2* __restrict__ AB,
                        const float* __restrict__ h, const int* __restrict__ idx2,
                        float* __restrict__ hperm,
                        float* __restrict__ ctA, float* __restrict__ ctB) {
  const int b = blockIdx.x >> 4;
  const int chunk = (blockIdx.x & 15) * 4 + (threadIdx.x >> 6);
  const int f = threadIdx.x & 63;
  const int s0 = chunk * CHS;

  float ta = 0.f, tb = 0.f;
#pragma unroll
  for (int g = 0; g < 2; ++g) {
    float hv[16]; float2 ab[16];
#pragma unroll
    for (int rr = 0; rr < 16; ++rr) {
      const int s = s0 + g * 16 + rr;
      const int j = idx2[b * N + s];
      hv[rr] = h[((size_t)b * N + j) * FOUT + f];
      ab[rr] = AB[b * N + s];
    }
#pragma unroll
    for (int rr = 0; rr < 16; ++rr) {
      const int s = s0 + g * 16 + rr;
      hperm[((size_t)b * N + s) * FOUT + f] = hv[rr];
      ta = fmaf(ab[rr].x, hv[rr], ta);
      tb = fmaf(ab[rr].y, hv[rr], tb);
    }
  }
  ctA[(b * NCH + chunk) * FOUT + f] = ta;
  ctB[(b * NCH + chunk) * FOUT + f] = tb;
}

// ---------------------------------------------------------------------------
// K5: slot-level PB (prefix of B*hperm) and SA (suffix of A*hperm) from chunk
// totals; all h access via hperm = streaming, no indirection. grid = B*16 x 256.
// ---------------------------------------------------------------------------
__global__ __launch_bounds__(256) void k_scan2(
    const float2* __restrict__ AB, const float* __restrict__ hperm,
    const float* __restrict__ ctA, const float* __restrict__ ctB,
    float* __restrict__ SA, float* __restrict__ PB) {
  __shared__ float cA[NCH * FOUT];  // 16 KB
  __shared__ float cB[NCH * FOUT];  // 16 KB
  const int b = blockIdx.x >> 4;
  const int chunk = (blockIdx.x & 15) * 4 + (threadIdx.x >> 6);
  const int f = threadIdx.x & 63;
  const int s0 = chunk * CHS;

  for (int t = threadIdx.x; t < NCH * FOUT; t += 256) {
    cA[t] = ctA[b * NCH * FOUT + t];
    cB[t] = ctB[b * NCH * FOUT + t];
  }
  __syncthreads();

  float offA = 0.f, offB = 0.f;
#pragma unroll 8
  for (int c2 = 0; c2 < NCH; ++c2) {
    const float va = cA[c2 * FOUT + f];
    const float vb = cB[c2 * FOUT + f];
    if (c2 > chunk) offA += va;
    if (c2 < chunk) offB += vb;
  }

  // forward prefix (PB)
  float run = offB;
#pragma unroll
  for (int g = 0; g < 2; ++g) {
    float hv[16]; float2 ab[16];
#pragma unroll
    for (int rr = 0; rr < 16; ++rr) {
      const int s = s0 + g * 16 + rr;
      hv[rr] = hperm[((size_t)b * N + s) * FOUT + f];
      ab[rr] = AB[b * N + s];
    }
#pragma unroll
    for (int rr = 0; rr < 16; ++rr) {
      run = fmaf(ab[rr].y, hv[rr], run);
      PB[((size_t)b * NP1 + s0 + g * 16 + rr + 1) * FOUT + f] = run;
    }
  }
  // backward suffix (SA)
  run = offA;
#pragma unroll
  for (int g = 1; g >= 0; --g) {
    float hv[16]; float2 ab[16];
#pragma unroll
    for (int rr = 0; rr < 16; ++rr) {
      const int s = s0 + g * 16 + rr;
      hv[rr] = hperm[((size_t)b * N + s) * FOUT + f];
      ab[rr] = AB[b * N + s];
    }
#pragma unroll
    for (int rr = 15; rr >= 0; --rr) {
      run = fmaf(ab[rr].x, hv[rr], run);
      SA[((size_t)b * NP1 + s0 + g * 16 + rr) * FOUT + f] = run;
    }
  }
  if (chunk == 0) {
    PB[((size_t)b * NP1 + 0) * FOUT + f] = 0.f;
    SA[((size_t)b * NP1 + N) * FOUT + f] = 0.f;
  }
}

// ---------------------------------------------------------------------------
// K6: per row i (one wave): q = bucket(-s1_i); sa = SA[se], pb = PB[sb],
//     boundary sweep over hperm (direct, no idx2 chain).
//     grid = B*N/4 x 256.
// ---------------------------------------------------------------------------
__global__ void k_out(const float* __restrict__ s1,
                      const int* __restrict__ start2,
                      const float* __restrict__ elemS2,
                      const float2* __restrict__ AB,
                      const float* __restrict__ hperm,
                      const float* __restrict__ SA,
                      const float* __restrict__ PB,
                      float* __restrict__ out) {
  const int wv = threadIdx.x >> 6;
  const int lane = threadIdx.x & 63;
  const int row = blockIdx.x * 4 + wv;
  const int b = row >> 11;
  const float s1v = s1[row];
  const float t = -s1v;
  const int q = bucketOf(t);
  const int sb = start2[b * KP1 + q];
  const int se = start2[b * KP1 + q + 1];

  float sa = SA[((size_t)b * NP1 + se) * FOUT + lane];  // all buckets > q
  float pb = PB[((size_t)b * NP1 + sb) * FOUT + lane];  // all buckets < q
  for (int s = sb; s < se; ++s) {
    const float s2v = elemS2[b * N + s];
    const float2 ab = AB[b * N + s];
    const float hv = hperm[((size_t)b * N + s) * FOUT + lane];
    if (s2v >= t) sa = fmaf(ab.x, hv, sa);
    else          pb = fmaf(ab.y, hv, pb);
  }
  const float uu = expf(s1v), uqv = expf(NS * s1v);
  const float v = uu * sa + uqv * pb;
  out[(size_t)row * FOUT + lane] = v >= 0.f ? v : NS * v;
}

extern "C" void kernel_launch(void* const* d_in, const int* in_sizes, int n_in,
                              void* d_out, int out_size, void* d_ws, size_t ws_size,
                              hipStream_t stream) {
  const float* x = (const float*)d_in[0];   // (8,2048,128)
  const float* W = (const float*)d_in[1];   // (128,64)
  const float* a = (const float*)d_in[2];   // (128,1)
  float* out = (float*)d_out;               // (8,2048,64)

  float* ws = (float*)d_ws;
  float* h = ws;                             // B*N*FOUT
  float* hperm = h + (size_t)B * N * FOUT;   // B*N*FOUT
  float* s1 = hperm + (size_t)B * N * FOUT;  // B*N each
  float* s2 = s1 + B * N;
  float* elemS1 = s2 + B * N;
  float* elemU = elemS1 + B * N;
  float* elemUq = elemU + B * N;
  float* elemS2 = elemUq + B * N;
  float* slotPrefU = elemS2 + B * N;         // B*NP1
  float* slotPrefQ = slotPrefU + B * NP1;
  float2* AB = (float2*)(slotPrefQ + B * NP1);  // B*N float2
  int* idx2 = (int*)(AB + (size_t)B * N);    // B*N
  int* start1 = idx2 + B * N;                // B*KP1
  int* start2 = start1 + B * KP1;
  float* ctA = (float*)(start2 + B * KP1);   // B*NCH*64
  float* ctB = ctA + (size_t)B * NCH * FOUT;
  float* SA = ctB + (size_t)B * NCH * FOUT;  // B*NP1*64
  float* PB = SA + (size_t)B * NP1 * FOUT;

  k_hs<<<B * N / RPB, 256, 0, stream>>>(x, W, a, h, s1, s2);
  k_bucket<<<2 * B, 1024, 0, stream>>>(s1, s2, start1, elemS1, elemU, elemUq,
                                       slotPrefU, slotPrefQ, start2, elemS2, idx2);
  k_z<<<B * (N / 256), 256, 0, stream>>>(elemS1, elemU, elemUq, slotPrefU,
                                         slotPrefQ, start1, elemS2, AB);
  k_scan1<<<B * 16, 256, 0, stream>>>(AB, h, idx2, hperm, ctA, ctB);
  k_scan2<<<B * 16, 256, 0, stream>>>(AB, hperm, ctA, ctB, SA, PB);
  k_out<<<B * N / 4, 256, 0, stream>>>(s1, start2, elemS2, AB, hperm, SA, PB, out);
}